// Round 9
// baseline (116.675 us; speedup 1.0000x reference)
//
#include <hip/hip_runtime.h>

#define NN 4096
#define DD 256
#define TEMP 0.07f
#define INV_T (1.0f / TEMP)
#define LOG2E 1.44269504089f
#define CEL (INV_T * LOG2E)      // el = exp2(s*CEL - CEL)
#define BLK 256
#define TB 64                    // tile block (rows per side)
#define NT (NN / TB)             // 64 tiles per side
#define NPAIR (NT * (NT + 1) / 2)   // 2080 upper-triangle blocks
#define M_E1 2.718281828f

typedef __attribute__((ext_vector_type(8))) short short8;
typedef __attribute__((ext_vector_type(4))) float f32x4;

__device__ __forceinline__ unsigned short f2bf(float x) {
    unsigned int b = __float_as_uint(x);
    return (unsigned short)((b + 0x7fffu + ((b >> 16) & 1u)) >> 16);
}

// sum across the 16-lane subgroup (xor 1,2,4,8 stays within the group)
__device__ __forceinline__ float row16_sum(float v) {
    v += __shfl_xor(v, 1, 64);
    v += __shfl_xor(v, 2, 64);
    v += __shfl_xor(v, 4, 64);
    v += __shfl_xor(v, 8, 64);
    return v;
}

// ---------------- convert F f32 -> bf16; zero out ----------------
__global__ __launch_bounds__(256) void cvt_k(const float* __restrict__ F,
                                             unsigned short* __restrict__ Fb,
                                             float* __restrict__ out) {
    int idx = blockIdx.x * 256 + threadIdx.x;
    float4 v = ((const float4*)F)[idx];
    ushort4 o;
    o.x = f2bf(v.x); o.y = f2bf(v.y); o.z = f2bf(v.z); o.w = f2bf(v.w);
    ((ushort4*)Fb)[idx] = o;
    if (idx == 0) out[0] = 0.f;
}

// ---------------- symmetric triangle stats kernel ----------------
// Block (I,J), J>=I, computes the 64x64 tile S[J-rows][I-rows] once.
// 8 stats per row (finalize derives the rest):
//   [0] S=sum es  [1] E=sum_{j!=i} el  [2] T=sum el*es  [3] a=sum_same' es
//   [4] f1=sum_same' el*es  [5] sg=sum_same' s  [6] sh=sum_same' s*es  [7] c=|same'|
// Off-diag blocks emit row-stats (I-rows, pR band J) AND col-stats (J-rows, pC band I).
__global__ __launch_bounds__(BLK, 4) void supcon_k(const unsigned short* __restrict__ Fb,
                                                   const int* __restrict__ labels,
                                                   float* __restrict__ pR,
                                                   float* __restrict__ pC) {
    __shared__ unsigned short sFi[TB * DD];   // 32 KB, 32-slot XOR swizzle; later sredR alias
    __shared__ int slabJ[TB];
    float* sredR = (float*)sFi;               // [4][64][8] = 8 KB after barrier

    const int tid = threadIdx.x;
    const int lane = tid & 63;
    const int wid = tid >> 6;                 // 0..3 = j-subtile
    const int il = lane & 15;                 // i-local within 16-tile
    const int kg = lane >> 4;                 // 0..3

    // ---- triangle decode: block b -> (I, J), J >= I ----
    const int b = blockIdx.x;
    int I = (int)((129.0f - sqrtf(16641.0f - 8.0f * (float)b)) * 0.5f);
    I = (I < 0) ? 0 : (I > NT - 1 ? NT - 1 : I);
    while ((I + 1) * NT - ((I + 1) * I) / 2 <= b) I++;
    while (I * NT - (I * (I - 1)) / 2 > b) I--;
    const int J = I + (b - (I * NT - (I * (I - 1)) / 2));
    const bool diag = (I == J);
    const int ibase = I * TB, jbase = J * TB;

    // ---- A-fragment loads (J-block rows); fly during LDS staging ----
    const short8* ap = (const short8*)Fb + (size_t)(jbase + wid * 16 + il) * 32 + kg;
    short8 af[8];
#pragma unroll
    for (int k = 0; k < 8; k++) af[k] = ap[k * 4];

    // ---- stage B (I-block rows) into LDS, 32-slot XOR swizzle ----
    for (int idx = tid; idx < TB * 32; idx += BLK) {
        int row = idx >> 5, c16 = idx & 31;
        short8 v = *(const short8*)(Fb + (size_t)(ibase + row) * DD + c16 * 8);
        *(short8*)(&sFi[row * DD + ((c16 ^ (row & 31)) * 8)]) = v;
    }
    if (tid < TB) slabJ[tid] = labels[jbase + tid];
    int li[4];
#pragma unroll
    for (int it = 0; it < 4; it++) li[it] = labels[ibase + it * 16 + il];
    __syncthreads();

    // ---- K-loop: 8 steps x 4 i-tiles ----
    f32x4 acc[4];
#pragma unroll
    for (int it = 0; it < 4; it++) acc[it] = (f32x4){0.f, 0.f, 0.f, 0.f};
#pragma unroll
    for (int k = 0; k < 8; k++) {
#pragma unroll
        for (int it = 0; it < 4; it++) {
            int rb = it * 16 + il;
            int slot = (4 * k + kg) ^ (rb & 31);
            short8 bf = *(const short8*)(&sFi[rb * DD + slot * 8]);
            acc[it] = __builtin_amdgcn_mfma_f32_16x16x32_bf16(af[k], bf, acc[it], 0, 0, 0);
        }
    }

    // ---- epilogue: element (jrow = wid*16+kg*4+r, icol = it*16+il) ----
    float st_r[4][8];
#pragma unroll
    for (int it = 0; it < 4; it++)
#pragma unroll
        for (int k = 0; k < 8; k++) st_r[it][k] = 0.f;

#pragma unroll
    for (int r = 0; r < 4; r++) {
        const int jrow = wid * 16 + kg * 4 + r;
        const int lj = slabJ[jrow];
        float cst[8];
#pragma unroll
        for (int k = 0; k < 8; k++) cst[k] = 0.f;
#pragma unroll
        for (int it = 0; it < 4; it++) {
            float s = acc[it][r];
            float es = exp2f(s * LOG2E);
            float el = exp2f(fmaf(s, CEL, -CEL));
            float t = el * es;
            float ses = s * es;
            bool same = (lj == li[it]);
            float msf, nsf;
            if (diag) {
                bool self = (jrow == it * 16 + il);
                msf = (same && !self) ? 1.f : 0.f;
                nsf = self ? 0.f : 1.f;
            } else {
                msf = same ? 1.f : 0.f;
                nsf = 1.f;
            }
            st_r[it][0] += es;
            st_r[it][1] = fmaf(nsf, el, st_r[it][1]);
            st_r[it][2] += t;
            st_r[it][3] = fmaf(msf, es, st_r[it][3]);
            st_r[it][4] = fmaf(msf, t, st_r[it][4]);
            st_r[it][5] = fmaf(msf, s, st_r[it][5]);
            st_r[it][6] = fmaf(msf, ses, st_r[it][6]);
            st_r[it][7] += msf;
            if (!diag) {
                cst[0] += es; cst[1] += el; cst[2] += t;
                cst[3] = fmaf(msf, es, cst[3]);
                cst[4] = fmaf(msf, t, cst[4]);
                cst[5] = fmaf(msf, s, cst[5]);
                cst[6] = fmaf(msf, ses, cst[6]);
                cst[7] += msf;
            }
        }
        // col-stats: reduce over the 16 il lanes, store row jrow
        if (!diag) {
#pragma unroll
            for (int k = 0; k < 8; k++) cst[k] = row16_sum(cst[k]);
            if (il == 0) {
                float* p = &pC[((size_t)I * NN + jbase + jrow) * 8];
                *(float4*)p = (float4){cst[0], cst[1], cst[2], cst[3]};
                *(float4*)(p + 4) = (float4){cst[4], cst[5], cst[6], cst[7]};
            }
        }
    }

    // ---- row-stats: reduce over kg lanes, merge waves via LDS, write pR ----
#pragma unroll
    for (int it = 0; it < 4; it++)
#pragma unroll
        for (int k = 0; k < 8; k++) {
            st_r[it][k] += __shfl_xor(st_r[it][k], 16, 64);
            st_r[it][k] += __shfl_xor(st_r[it][k], 32, 64);
        }
    __syncthreads();   // sFi reads done; alias as sredR
    if (kg == 0) {
#pragma unroll
        for (int it = 0; it < 4; it++)
#pragma unroll
            for (int k = 0; k < 8; k++)
                sredR[(wid * TB + it * 16 + il) * 8 + k] = st_r[it][k];
    }
    __syncthreads();
    {
        const int row = tid >> 2;             // 64 rows x 8 stats = 512, 256 thr x 2
        const int k2 = (tid & 3) * 2;
        float v0 = 0.f, v1 = 0.f;
#pragma unroll
        for (int w = 0; w < 4; w++) {
            v0 += sredR[(w * TB + row) * 8 + k2];
            v1 += sredR[(w * TB + row) * 8 + k2 + 1];
        }
        float* p = &pR[((size_t)J * NN + ibase + row) * 8 + k2];
        p[0] = v0; p[1] = v1;
    }
}

// ---------------- finalize: merge bands, compute loss ----------------
__global__ __launch_bounds__(256) void finalize_k(const float* __restrict__ pR,
                                                  const float* __restrict__ pC,
                                                  float* __restrict__ out) {
    __shared__ float sacc[4];
    const int t = threadIdx.x;
    const int i = blockIdx.x * 256 + t;
    const int ti = i >> 6;

    float st[8];
#pragma unroll
    for (int k = 0; k < 8; k++) st[k] = 0.f;
    for (int band = 0; band < NT; band++) {
        const float* p = (band >= ti) ? (pR + ((size_t)band * NN + i) * 8)
                                      : (pC + ((size_t)band * NN + i) * 8);
        float4 x = *(const float4*)p;
        float4 y = *(const float4*)(p + 4);
        st[0] += x.x; st[1] += x.y; st[2] += x.z; st[3] += x.w;
        st[4] += y.x; st[5] += y.y; st[6] += y.z; st[7] += y.w;
    }
    float S = st[0], E = st[1], T = st[2], a = st[3];
    float f1 = st[4], sg = st[5], sh = st[6], c = st[7];
    float g = (sg - c) * INV_T;
    float h = (sh - a) * INV_T;
    float b2 = S - a - M_E1;
    float f2 = T - f1 - M_E1;
    float As = (a > 0.f) ? a : 1.f;
    float Bd = (b2 > 0.f) ? b2 : 1.f;
    float Z = E + f2 / Bd - f1 / As;
    float Q = g - h / As;
    float P = c - ((a > 0.f) ? 1.f : 0.f);
    float ms = (c > 0.f) ? c : 1.f;
    float loss_i = -(Q - P * logf(Z + 1e-8f)) / ms;

    float v = loss_i;
#pragma unroll
    for (int off = 32; off > 0; off >>= 1) v += __shfl_xor(v, off, 64);
    if ((t & 63) == 0) sacc[t >> 6] = v;
    __syncthreads();
    if (t == 0) atomicAdd(out, (sacc[0] + sacc[1] + sacc[2] + sacc[3]) * (1.0f / NN));
}

extern "C" void kernel_launch(void* const* d_in, const int* in_sizes, int n_in,
                              void* d_out, int out_size, void* d_ws, size_t ws_size,
                              hipStream_t stream) {
    const float* F = (const float*)d_in[0];
    const int* labels = (const int*)d_in[1];
    float* out = (float*)d_out;
    unsigned short* Fb = (unsigned short*)d_ws;                       // 2 MB
    float* pR = (float*)((char*)d_ws + (size_t)2 * 1024 * 1024);      // 8 MB  [NT][NN][8]
    float* pC = (float*)((char*)d_ws + (size_t)10 * 1024 * 1024);     // 8 MB  [NT][NN][8]

    cvt_k<<<NN * DD / 4 / 256, 256, 0, stream>>>(F, Fb, out);
    supcon_k<<<NPAIR, BLK, 0, stream>>>(Fb, labels, pR, pC);
    finalize_k<<<NN / 256, 256, 0, stream>>>(pR, pC, out);
}

// Round 10
// 93.173 us; speedup vs baseline: 1.2522x; 1.2522x over previous
//
#include <hip/hip_runtime.h>

#define NN 4096
#define DD 256
#define TEMP 0.07f
#define INV_T (1.0f / TEMP)
#define LOG2E 1.44269504089f
#define CEL (INV_T * LOG2E)      // el = exp2(s*CEL - CEL)
#define BLK 256
#define IB 64             // i-rows per block (4 tiles of 16)
#define JC 32             // j-chunks
#define JPC (NN / JC)     // 128 j per chunk: 4 waves x 2 tiles x 16
#define GRID ((NN / IB) * JC)   // 2048 blocks
#define M_E1 2.718281828f

typedef __attribute__((ext_vector_type(8))) short short8;
typedef __attribute__((ext_vector_type(4))) float f32x4;

__device__ __forceinline__ unsigned short f2bf(float x) {
    unsigned int b = __float_as_uint(x);
    return (unsigned short)((b + 0x7fffu + ((b >> 16) & 1u)) >> 16);
}

// ---------------- convert F f32 -> bf16; zero out ----------------
__global__ __launch_bounds__(256) void cvt_k(const float* __restrict__ F,
                                             unsigned short* __restrict__ Fb,
                                             float* __restrict__ out) {
    int idx = blockIdx.x * 256 + threadIdx.x;
    float4 v = ((const float4*)F)[idx];
    ushort4 o;
    o.x = f2bf(v.x); o.y = f2bf(v.y); o.z = f2bf(v.z); o.w = f2bf(v.w);
    ((ushort4*)Fb)[idx] = o;
    if (idx == 0) out[0] = 0.f;
}

// ---------------- single-pass stats kernel, 16x16x32 MFMA ----------------
// Per row i, 8 stats (l=(s-1)/T derived in finalize):
//   [0] S=sum es  [1] E=sum_{j!=i} el  [2] T=sum el*es  [3] a=sum_same' es
//   [4] f1=sum_same' el*es  [5] sg=sum_same' s  [6] sh=sum_same' s*es  [7] c=|same'|
__global__ __launch_bounds__(BLK) void supcon_k(const unsigned short* __restrict__ Fb,
                                                const int* __restrict__ labels,
                                                float* __restrict__ partial) {
    __shared__ unsigned short sFi[IB * DD];   // 32 KB, 32-slot XOR swizzle
    __shared__ int slab[JPC];                 // 512 B
    float* sred = (float*)sFi;                // aliased after compute: [4][64][8]

    const int tid = threadIdx.x;
    const int lane = tid & 63;
    const int wid = tid >> 6;                 // 0..3
    const int il = lane & 15;                 // i-local within 16-tile / A row within tile
    const int kg = lane >> 4;                 // 0..3
    const int ib = blockIdx.x >> 5;
    const int jc = blockIdx.x & (JC - 1);
    const int i0 = ib * IB;
    const int jb0 = jc * JPC + (wid * 2) * 16;   // tile 0
    const int jb1 = jb0 + 16;                     // tile 1

    // ---- tile-0 A-fragments first (fly during LDS staging) ----
    const short8* ap0 = (const short8*)Fb + (size_t)(jb0 + il) * 32 + kg;
    const short8* ap1 = ap0 + 512;               // +16 rows
    short8 af[8];
#pragma unroll
    for (int k = 0; k < 8; k++) af[k] = ap0[k * 4];

    // ---- stage i-rows into LDS, 32-slot XOR swizzle ----
    for (int idx = tid; idx < IB * 32; idx += BLK) {
        int row = idx >> 5, c16 = idx & 31;
        short8 v = *(const short8*)(Fb + (size_t)(i0 + row) * DD + c16 * 8);
        *(short8*)(&sFi[row * DD + ((c16 ^ (row & 31)) * 8)]) = v;
    }
    if (tid < JPC) slab[tid] = labels[jc * JPC + tid];
    int li[4];
#pragma unroll
    for (int it = 0; it < 4; it++) li[it] = labels[i0 + it * 16 + il];
    __syncthreads();

    const bool hasdiag = (jc == (i0 >> 7));

#define KLOOP(ACC)                                                              \
    {                                                                           \
_Pragma("unroll")                                                               \
        for (int k = 0; k < 8; k++) {                                           \
_Pragma("unroll")                                                               \
            for (int it = 0; it < 4; it++) {                                    \
                int rb = it * 16 + il;                                          \
                int slot = (4 * k + kg) ^ (rb & 31);                            \
                short8 bf = *(const short8*)(&sFi[rb * DD + slot * 8]);         \
                ACC[it] = __builtin_amdgcn_mfma_f32_16x16x32_bf16(af[k], bf, ACC[it], 0, 0, 0); \
            }                                                                   \
        }                                                                       \
    }

#define EPILOGUE(ACC, JB)                                                       \
    {                                                                           \
_Pragma("unroll")                                                               \
        for (int r = 0; r < 4; r++) {                                           \
            const int jg = (JB) + kg * 4 + r;                                   \
            const int lj = slab[jg - jc * JPC];                                 \
_Pragma("unroll")                                                               \
            for (int it = 0; it < 4; it++) {                                    \
                float s = ACC[it][r];                                           \
                const int ig = i0 + it * 16 + il;                               \
                bool same = (lj == li[it]);                                     \
                bool self = hasdiag && (jg == ig);                              \
                float msf = (same && !self) ? 1.f : 0.f;                        \
                float nsf = self ? 0.f : 1.f;                                   \
                float es = exp2f(s * LOG2E);                                    \
                float el = exp2f(fmaf(s, CEL, -CEL));                           \
                float t  = el * es;                                             \
                float ses = s * es;                                             \
                st[it][0] += es;                                                \
                st[it][1] = fmaf(nsf, el, st[it][1]);                           \
                st[it][2] += t;                                                 \
                st[it][3] = fmaf(msf, es, st[it][3]);                           \
                st[it][4] = fmaf(msf, t,  st[it][4]);                           \
                st[it][5] = fmaf(msf, s,  st[it][5]);                           \
                st[it][6] = fmaf(msf, ses, st[it][6]);                          \
                st[it][7] += msf;                                               \
            }                                                                   \
        }                                                                       \
    }

    // ---- tile 0 ----
    f32x4 acc[4];
#pragma unroll
    for (int it = 0; it < 4; it++) acc[it] = (f32x4){0.f, 0.f, 0.f, 0.f};
    KLOOP(acc)

    // issue tile-1 A loads now (reuse af regs); tile-0 epilogue hides latency
#pragma unroll
    for (int k = 0; k < 8; k++) af[k] = ap1[k * 4];

    float st[4][8];
#pragma unroll
    for (int it = 0; it < 4; it++)
#pragma unroll
        for (int k = 0; k < 8; k++) st[it][k] = 0.f;

    EPILOGUE(acc, jb0)

    asm volatile("" ::: "memory");   // block LDS-load CSE across tiles

    // ---- tile 1 ----
#pragma unroll
    for (int it = 0; it < 4; it++) acc[it] = (f32x4){0.f, 0.f, 0.f, 0.f};
    KLOOP(acc)
    EPILOGUE(acc, jb1)

    // ---- reduce over kg lanes ----
#pragma unroll
    for (int it = 0; it < 4; it++)
#pragma unroll
        for (int k = 0; k < 8; k++) {
            st[it][k] += __shfl_xor(st[it][k], 16, 64);
            st[it][k] += __shfl_xor(st[it][k], 32, 64);
        }

    __syncthreads();   // sFi reads done; alias as sred
    if (kg == 0) {
#pragma unroll
        for (int it = 0; it < 4; it++)
#pragma unroll
            for (int k = 0; k < 8; k++)
                sred[(wid * IB + it * 16 + il) * 8 + k] = st[it][k];
    }
    __syncthreads();
    {
        const int row = tid >> 2;             // 64 rows x 8 stats = 512, 256 thr x 2
        const int k2 = (tid & 3) * 2;
        float v0 = 0.f, v1 = 0.f;
#pragma unroll
        for (int w = 0; w < 4; w++) {
            v0 += sred[(w * IB + row) * 8 + k2];
            v1 += sred[(w * IB + row) * 8 + k2 + 1];
        }
        float* p = &partial[((size_t)jc * NN + i0 + row) * 8 + k2];
        p[0] = v0; p[1] = v1;
    }
}

// ---------------- finalize: merge chunks, compute loss ----------------
__global__ __launch_bounds__(256) void finalize_k(const float* __restrict__ partial,
                                                  float* __restrict__ out) {
    __shared__ float sacc[4];
    const int t = threadIdx.x;
    const int i = blockIdx.x * 256 + t;

    float st[8];
#pragma unroll
    for (int k = 0; k < 8; k++) st[k] = 0.f;
    for (int jc = 0; jc < JC; jc++) {
        const float4* p = (const float4*)&partial[((size_t)jc * NN + i) * 8];
        float4 x = p[0], y = p[1];
        st[0] += x.x; st[1] += x.y; st[2] += x.z; st[3] += x.w;
        st[4] += y.x; st[5] += y.y; st[6] += y.z; st[7] += y.w;
    }
    float S = st[0], E = st[1], T = st[2], a = st[3];
    float f1 = st[4], sg = st[5], sh = st[6], c = st[7];
    float g = (sg - c) * INV_T;
    float h = (sh - a) * INV_T;
    float b2 = S - a - M_E1;
    float f2 = T - f1 - M_E1;
    float As = (a > 0.f) ? a : 1.f;
    float Bd = (b2 > 0.f) ? b2 : 1.f;
    float Z = E + f2 / Bd - f1 / As;
    float Q = g - h / As;
    float P = c - ((a > 0.f) ? 1.f : 0.f);
    float ms = (c > 0.f) ? c : 1.f;
    float loss_i = -(Q - P * logf(Z + 1e-8f)) / ms;

    float v = loss_i;
#pragma unroll
    for (int off = 32; off > 0; off >>= 1) v += __shfl_xor(v, off, 64);
    if ((t & 63) == 0) sacc[t >> 6] = v;
    __syncthreads();
    if (t == 0) atomicAdd(out, (sacc[0] + sacc[1] + sacc[2] + sacc[3]) * (1.0f / NN));
}

extern "C" void kernel_launch(void* const* d_in, const int* in_sizes, int n_in,
                              void* d_out, int out_size, void* d_ws, size_t ws_size,
                              hipStream_t stream) {
    const float* F = (const float*)d_in[0];
    const int* labels = (const int*)d_in[1];
    float* out = (float*)d_out;
    unsigned short* Fb = (unsigned short*)d_ws;                   // 2 MB
    float* partial = (float*)((char*)d_ws + (size_t)NN * DD * 2); // 4 MB (JC*NN*8 floats)

    cvt_k<<<NN * DD / 4 / 256, 256, 0, stream>>>(F, Fb, out);
    supcon_k<<<GRID, BLK, 0, stream>>>(Fb, labels, partial);
    finalize_k<<<NN / 256, 256, 0, stream>>>(partial, out);
}